// Round 1
// baseline (219.159 us; speedup 1.0000x reference)
//
#include <hip/hip_runtime.h>
#include <hip/hip_bf16.h>
#include <math.h>

// Problem constants (match reference setup_inputs)
#define DIMD 128
#define NB   16384   // B  word pairs
#define NK   10      // K  negatives
#define NB2  8192    // B2 mwe batch
#define NL   5       // L  max entity len
#define NW   10      // W  context width

// -log_sigmoid(x) = softplus(-x); stable softplus(z) = max(z,0) + log1p(exp(-|z|))
__device__ __forceinline__ float softplus_f(float z) {
  return fmaxf(z, 0.0f) + log1pf(__expf(-fabsf(z)));
}

// full 64-lane butterfly sum; all lanes end with the total
__device__ __forceinline__ float wred64(float v) {
  v += __shfl_xor(v, 32);
  v += __shfl_xor(v, 16);
  v += __shfl_xor(v, 8);
  v += __shfl_xor(v, 4);
  v += __shfl_xor(v, 2);
  v += __shfl_xor(v, 1);
  return v;
}

__device__ __forceinline__ float2 row2(const float* __restrict__ tab, int idx, int lane) {
  return *reinterpret_cast<const float2*>(tab + (size_t)idx * DIMD + 2 * lane);
}

// ---------------- word-level SGNS: one wave per pair ----------------
__global__ __launch_bounds__(256) void k_words(
    const float* __restrict__ ct, const float* __restrict__ xt,
    const int* __restrict__ wc, const int* __restrict__ wo,
    const int* __restrict__ wn, float* __restrict__ partials) {
  const int tid  = blockIdx.x * 256 + threadIdx.x;
  const int b    = tid >> 6;            // grid sized so b < NB always
  const int lane = threadIdx.x & 63;

  const int ci = wc[b];
  const int oi = wo[b];
  const float2 ce = row2(ct, ci, lane);
  const float2 oe = row2(xt, oi, lane);

  int ni[NK];
#pragma unroll
  for (int k = 0; k < NK; ++k) ni[k] = wn[b * NK + k];
  float2 nv[NK];
#pragma unroll
  for (int k = 0; k < NK; ++k) nv[k] = row2(xt, ni[k], lane);

  float wsum = softplus_f(-wred64(ce.x * oe.x + ce.y * oe.y));  // pos term
#pragma unroll
  for (int k = 0; k < NK; ++k)
    wsum += softplus_f(wred64(ce.x * nv[k].x + ce.y * nv[k].y)); // neg terms

  __shared__ float sm[4];
  if (lane == 0) sm[threadIdx.x >> 6] = wsum;
  __syncthreads();
  if (threadIdx.x == 0)
    partials[blockIdx.x] = (sm[0] + sm[1]) + (sm[2] + sm[3]);
}

// ---------------- MWE SGNS: one wave per B2 row (handles all W contexts) ----------------
__global__ __launch_bounds__(256) void k_mwe(
    const float* __restrict__ ct, const float* __restrict__ xt,
    const int* __restrict__ mc, const int* __restrict__ mlen,
    const int* __restrict__ mo, const int* __restrict__ mn,
    float2* __restrict__ partials) {
  const int tid  = blockIdx.x * 256 + threadIdx.x;
  const int g    = tid >> 6;            // grid sized so g < NB2 always
  const int lane = threadIdx.x & 63;

  float wsum = 0.0f, wcnt = 0.0f;

  // masked mean over first len tokens, kept in registers (2 floats/lane)
  const int len = mlen[g];
  float mx = 0.0f, my = 0.0f;
  for (int t = 0; t < len; ++t) {
    const float2 v = row2(ct, mc[g * NL + t], lane);
    mx += v.x; my += v.y;
  }
  const float inv = 1.0f / (float)len;
  mx *= inv; my *= inv;

  for (int w = 0; w < NW; ++w) {
    const int o = mo[g * NW + w];
    if (o == 0) continue;               // pad token -> vf = 0, contributes nothing
    const int* __restrict__ nrow = mn + (size_t)(g * NW + w) * NK;
    int ni[NK];
#pragma unroll
    for (int k = 0; k < NK; ++k) ni[k] = nrow[k];
    const float2 oe = row2(xt, o, lane);
    float2 nv[NK];
#pragma unroll
    for (int k = 0; k < NK; ++k) nv[k] = row2(xt, ni[k], lane);

    float term = softplus_f(-wred64(mx * oe.x + my * oe.y));
#pragma unroll
    for (int k = 0; k < NK; ++k)
      term += softplus_f(wred64(mx * nv[k].x + my * nv[k].y));
    wsum += term;
    wcnt += 1.0f;
  }

  __shared__ float sm[4], sc[4];
  if (lane == 0) { sm[threadIdx.x >> 6] = wsum; sc[threadIdx.x >> 6] = wcnt; }
  __syncthreads();
  if (threadIdx.x == 0)
    partials[blockIdx.x] = make_float2((sm[0] + sm[1]) + (sm[2] + sm[3]),
                                       (sc[0] + sc[1]) + (sc[2] + sc[3]));
}

// ---------------- deterministic final reduction ----------------
__global__ __launch_bounds__(256) void k_final(
    const float* __restrict__ wp, const float2* __restrict__ mp,
    float* __restrict__ out) {
  __shared__ float sa[256], sb[256], sc[256];
  float s = 0.0f;
  for (int i = threadIdx.x; i < NB / 4; i += 256) s += wp[i];
  float ms = 0.0f, mcn = 0.0f;
  for (int i = threadIdx.x; i < NB2 / 4; i += 256) {
    const float2 v = mp[i];
    ms += v.x; mcn += v.y;
  }
  sa[threadIdx.x] = s; sb[threadIdx.x] = ms; sc[threadIdx.x] = mcn;
  __syncthreads();
  if (threadIdx.x == 0) {
    float S = 0.0f, MS = 0.0f, MC = 0.0f;
    for (int i = 0; i < 256; ++i) { S += sa[i]; MS += sb[i]; MC += sc[i]; }
    out[0] = S / (float)NB + 25.0f * (MS / fmaxf(MC, 1.0f));
  }
}

extern "C" void kernel_launch(void* const* d_in, const int* in_sizes, int n_in,
                              void* d_out, int out_size, void* d_ws, size_t ws_size,
                              hipStream_t stream) {
  const float* ct   = (const float*)d_in[0];  // center_table  (VOCAB, 128)
  const float* xt   = (const float*)d_in[1];  // context_table (VOCAB, 128)
  const int*   wc   = (const int*)d_in[2];    // w_center  (B,)
  const int*   wo   = (const int*)d_in[3];    // w_outside (B,)
  const int*   wn   = (const int*)d_in[4];    // w_neg     (B,K)
  const int*   mc   = (const int*)d_in[5];    // m_center  (B2,L)
  const int*   mlen = (const int*)d_in[6];    // m_len     (B2,)
  const int*   mo   = (const int*)d_in[7];    // m_outside (B2,W)
  const int*   mn   = (const int*)d_in[8];    // m_neg     (B2*W,K)

  float*  wp = (float*)d_ws;            // NB/4  = 4096 floats (word partials)
  float2* mp = (float2*)(wp + NB / 4);  // NB2/4 = 2048 float2 (mwe sum,count) — 16KB offset, 8B aligned

  k_words<<<NB / 4, 256, 0, stream>>>(ct, xt, wc, wo, wn, wp);
  k_mwe<<<NB2 / 4, 256, 0, stream>>>(ct, xt, mc, mlen, mo, mn, mp);
  k_final<<<1, 256, 0, stream>>>(wp, mp, (float*)d_out);
}

// Round 2
// 104.799 us; speedup vs baseline: 2.0912x; 2.0912x over previous
//
#include <hip/hip_runtime.h>
#include <hip/hip_bf16.h>
#include <math.h>

// Problem constants (match reference setup_inputs)
#define DIMD 128
#define NB   16384   // B  word pairs
#define NK   10      // K  negatives
#define NB2  8192    // B2 mwe batch
#define NL   5       // L  max entity len
#define NW   10      // W  context width

// fast stable softplus: max(z,0) + log(1+exp(-|z|)), hardware exp/log
__device__ __forceinline__ float softplus_fast(float z) {
  return fmaxf(z, 0.0f) + __logf(1.0f + __expf(-fabsf(z)));
}

// Reduce-scatter 16 per-lane partial values across the 64-lane wave.
// Returns: each lane holds the FULL 64-lane sum of value index
//   idx = 8*b5 + 4*b4 + 2*b3 + b2   (lane bits)
// (each value replicated on the 4 lanes sharing bits 5..2).
// Cost: 17 shuffles + 17 adds (vs 96 shuffles for 16 independent butterflies).
__device__ __forceinline__ float rs16(float v[16], int lane) {
  const bool b5 = (lane & 32) != 0, b4 = (lane & 16) != 0;
  const bool b3 = (lane & 8) != 0,  b2 = (lane & 4) != 0;
#pragma unroll
  for (int j = 0; j < 8; ++j) {
    float send = b5 ? v[j] : v[j + 8];
    float recv = __shfl_xor(send, 32);
    v[j] = (b5 ? v[j + 8] : v[j]) + recv;
  }
#pragma unroll
  for (int j = 0; j < 4; ++j) {
    float send = b4 ? v[j] : v[j + 4];
    float recv = __shfl_xor(send, 16);
    v[j] = (b4 ? v[j + 4] : v[j]) + recv;
  }
#pragma unroll
  for (int j = 0; j < 2; ++j) {
    float send = b3 ? v[j] : v[j + 2];
    float recv = __shfl_xor(send, 8);
    v[j] = (b3 ? v[j + 2] : v[j]) + recv;
  }
  {
    float send = b2 ? v[0] : v[1];
    float recv = __shfl_xor(send, 4);
    v[0] = (b2 ? v[1] : v[0]) + recv;
  }
  float s = v[0];
  s += __shfl_xor(s, 2);
  s += __shfl_xor(s, 1);
  return s;
}

__device__ __forceinline__ float wred64(float v) {
  v += __shfl_xor(v, 32);
  v += __shfl_xor(v, 16);
  v += __shfl_xor(v, 8);
  v += __shfl_xor(v, 4);
  v += __shfl_xor(v, 2);
  v += __shfl_xor(v, 1);
  return v;
}

__device__ __forceinline__ float2 row2(const float* __restrict__ tab, int idx, int lane) {
  return *reinterpret_cast<const float2*>(tab + (size_t)idx * DIMD + 2 * lane);
}

// ---------------- word-level SGNS: one wave per pair ----------------
__global__ __launch_bounds__(256) void k_words(
    const float* __restrict__ ct, const float* __restrict__ xt,
    const int* __restrict__ wc, const int* __restrict__ wo,
    const int* __restrict__ wn, float* __restrict__ partials) {
  const int tid  = blockIdx.x * 256 + threadIdx.x;
  const int b    = tid >> 6;
  const int lane = threadIdx.x & 63;
  // lane-constant: which dot index this lane ends up owning after rs16
  const int   idx   = ((lane >> 5) & 1) * 8 + ((lane >> 4) & 1) * 4 +
                      ((lane >> 3) & 1) * 2 + ((lane >> 2) & 1);
  const float zsgn  = (idx == 0) ? -1.0f : 1.0f;            // pos term gets -dot
  const float wmask = (((lane & 3) == 0) && idx <= 10) ? 1.0f : 0.0f;

  const float2 ce = row2(ct, wc[b], lane);
  const float2 oe = row2(xt, wo[b], lane);

  int ni[NK];
#pragma unroll
  for (int k = 0; k < NK; ++k) ni[k] = wn[b * NK + k];
  float2 nv[NK];
#pragma unroll
  for (int k = 0; k < NK; ++k) nv[k] = row2(xt, ni[k], lane);

  float v[16];
  v[0] = ce.x * oe.x + ce.y * oe.y;
#pragma unroll
  for (int k = 0; k < NK; ++k) v[1 + k] = ce.x * nv[k].x + ce.y * nv[k].y;
#pragma unroll
  for (int j = 11; j < 16; ++j) v[j] = 0.0f;

  const float s = rs16(v, lane);
  float wsum = wred64(softplus_fast(s * zsgn) * wmask);

  __shared__ float sm[4];
  if (lane == 0) sm[threadIdx.x >> 6] = wsum;
  __syncthreads();
  if (threadIdx.x == 0)
    partials[blockIdx.x] = (sm[0] + sm[1]) + (sm[2] + sm[3]);
}

// ---------------- MWE SGNS: one wave per B2 row (all W contexts) ----------------
__global__ __launch_bounds__(256) void k_mwe(
    const float* __restrict__ ct, const float* __restrict__ xt,
    const int* __restrict__ mc, const int* __restrict__ mlen,
    const int* __restrict__ mo, const int* __restrict__ mn,
    float2* __restrict__ partials) {
  const int tid  = blockIdx.x * 256 + threadIdx.x;
  const int g    = tid >> 6;
  const int lane = threadIdx.x & 63;
  const int   idx   = ((lane >> 5) & 1) * 8 + ((lane >> 4) & 1) * 4 +
                      ((lane >> 3) & 1) * 2 + ((lane >> 2) & 1);
  const float zsgn  = (idx == 0) ? -1.0f : 1.0f;
  const float wmask = (((lane & 3) == 0) && idx <= 10) ? 1.0f : 0.0f;

  // masked mean over first len tokens (len is wave-uniform)
  const int len = mlen[g];
  float mx = 0.0f, my = 0.0f;
  for (int t = 0; t < len; ++t) {
    const float2 e = row2(ct, mc[g * NL + t], lane);
    mx += e.x; my += e.y;
  }
  const float inv = 1.0f / (float)len;
  mx *= inv; my *= inv;

  float wsum = 0.0f, wcnt = 0.0f;
  for (int w = 0; w < NW; ++w) {
    const int o = mo[g * NW + w];
    if (o == 0) continue;            // pad: vf=0 (wave-uniform branch)
    const int* __restrict__ nrow = mn + (size_t)(g * NW + w) * NK;
    int ni[NK];
#pragma unroll
    for (int k = 0; k < NK; ++k) ni[k] = nrow[k];
    const float2 oe = row2(xt, o, lane);
    float2 nv[NK];
#pragma unroll
    for (int k = 0; k < NK; ++k) nv[k] = row2(xt, ni[k], lane);

    float v[16];
    v[0] = mx * oe.x + my * oe.y;
#pragma unroll
    for (int k = 0; k < NK; ++k) v[1 + k] = mx * nv[k].x + my * nv[k].y;
#pragma unroll
    for (int j = 11; j < 16; ++j) v[j] = 0.0f;

    const float s = rs16(v, lane);
    wsum += softplus_fast(s * zsgn) * wmask;   // per-lane; reduced once at end
    wcnt += 1.0f;
  }

  wsum = wred64(wsum);

  __shared__ float sm[4], sc[4];
  if (lane == 0) { sm[threadIdx.x >> 6] = wsum; sc[threadIdx.x >> 6] = wcnt; }
  __syncthreads();
  if (threadIdx.x == 0)
    partials[blockIdx.x] = make_float2((sm[0] + sm[1]) + (sm[2] + sm[3]),
                                       (sc[0] + sc[1]) + (sc[2] + sc[3]));
}

// ---------------- deterministic final reduction ----------------
__global__ __launch_bounds__(256) void k_final(
    const float* __restrict__ wp, const float2* __restrict__ mp,
    float* __restrict__ out) {
  __shared__ float sa[256], sb[256], sc[256];
  float s = 0.0f;
  for (int i = threadIdx.x; i < NB / 4; i += 256) s += wp[i];
  float ms = 0.0f, mcn = 0.0f;
  for (int i = threadIdx.x; i < NB2 / 4; i += 256) {
    const float2 v = mp[i];
    ms += v.x; mcn += v.y;
  }
  sa[threadIdx.x] = s; sb[threadIdx.x] = ms; sc[threadIdx.x] = mcn;
  __syncthreads();
  if (threadIdx.x == 0) {
    float S = 0.0f, MS = 0.0f, MC = 0.0f;
    for (int i = 0; i < 256; ++i) { S += sa[i]; MS += sb[i]; MC += sc[i]; }
    out[0] = S / (float)NB + 25.0f * (MS / fmaxf(MC, 1.0f));
  }
}

extern "C" void kernel_launch(void* const* d_in, const int* in_sizes, int n_in,
                              void* d_out, int out_size, void* d_ws, size_t ws_size,
                              hipStream_t stream) {
  const float* ct   = (const float*)d_in[0];  // center_table  (VOCAB, 128)
  const float* xt   = (const float*)d_in[1];  // context_table (VOCAB, 128)
  const int*   wc   = (const int*)d_in[2];
  const int*   wo   = (const int*)d_in[3];
  const int*   wn   = (const int*)d_in[4];
  const int*   mc   = (const int*)d_in[5];
  const int*   mlen = (const int*)d_in[6];
  const int*   mo   = (const int*)d_in[7];
  const int*   mn   = (const int*)d_in[8];

  float*  wp = (float*)d_ws;            // NB/4 floats
  float2* mp = (float2*)(wp + NB / 4);  // NB2/4 float2

  k_words<<<NB / 4, 256, 0, stream>>>(ct, xt, wc, wo, wn, wp);
  k_mwe<<<NB2 / 4, 256, 0, stream>>>(ct, xt, mc, mlen, mo, mn, mp);
  k_final<<<1, 256, 0, stream>>>(wp, mp, (float*)d_out);
}